// Round 1
// baseline (392.455 us; speedup 1.0000x reference)
//
#include <hip/hip_runtime.h>
#include <hip/hip_bf16.h>
#include <stdint.h>

// Problem dims (fixed by reference)
#define B_DIM 8
#define S_DIM 2048
#define M_TOT 16384   // B*S rows of x
#define K_TOT 2048    // M_DIM (inner/contraction dim)
#define N_TOT 2048    // N_DIM (output cols)

// GEMM tile config (m97 structure: 128x128 tile, BK=32, 4 waves, 4x4 MFMA acc/wave)
#define BM 128
#define BN 128
#define BK 32

typedef __attribute__((ext_vector_type(8))) short short8;
typedef __attribute__((ext_vector_type(4))) float float4v;
typedef __attribute__((ext_vector_type(8))) unsigned short ushort8;

__device__ __forceinline__ unsigned short f2bf(float f) {
    union { float f; unsigned u; } a; a.f = f;
    // round-to-nearest-even bf16
    unsigned r = a.u + 0x7FFFu + ((a.u >> 16) & 1u);
    return (unsigned short)(r >> 16);
}

// ---- Kernel 1: cast x fp32 -> bf16, 8 elems/thread, fully coalesced ----
__global__ void cast_x_kernel(const float* __restrict__ x, unsigned short* __restrict__ xb) {
    int i = blockIdx.x * blockDim.x + threadIdx.x;   // handles 8 floats
    const float4* xf = (const float4*)x;
    float4 a = xf[2 * i];
    float4 b = xf[2 * i + 1];
    ushort8 o;
    o[0] = f2bf(a.x); o[1] = f2bf(a.y); o[2] = f2bf(a.z); o[3] = f2bf(a.w);
    o[4] = f2bf(b.x); o[5] = f2bf(b.y); o[6] = f2bf(b.z); o[7] = f2bf(b.w);
    ((ushort8*)xb)[i] = o;
}

// ---- Kernel 2: zero dense W (8 MB), float4 stores ----
__global__ void zero_kernel(float4* __restrict__ p) {
    int i = blockIdx.x * blockDim.x + threadIdx.x;
    p[i] = float4{0.f, 0.f, 0.f, 0.f};
}

// ---- Kernel 3: CSR scatter -> dense bf16 W[N][K_TOT] (row-major = B^T layout) ----
__global__ void scatter_kernel(const float* __restrict__ val, const int* __restrict__ idx,
                               const int* __restrict__ indptr, unsigned short* __restrict__ Wb) {
    int n = blockIdx.x;
    int s = indptr[n], e = indptr[n + 1];
    for (int j = s + threadIdx.x; j < e; j += blockDim.x) {
        Wb[(size_t)n * K_TOT + idx[j]] = f2bf(val[j]);
    }
}

// ---- Kernel 4: bf16 GEMM C[M][N] = A[M][K] * W[N][K]^T + bias, fp32 out ----
// 256 threads = 4 waves; each wave computes a 64x64 subtile as 4x4 of 16x16x32 MFMA.
__global__ __launch_bounds__(256) void gemm_bias_kernel(
    const unsigned short* __restrict__ A,   // x_bf [M_TOT][K_TOT]
    const unsigned short* __restrict__ Bw,  // W_bf [N_TOT][K_TOT]
    const float* __restrict__ bias,         // [N_TOT]
    float* __restrict__ C)                  // [M_TOT][N_TOT]
{
    __shared__ unsigned short Asm[BM * BK];  // 8 KB
    __shared__ unsigned short Bsm[BN * BK];  // 8 KB

    const int tid  = threadIdx.x;
    const int lane = tid & 63;
    const int wave = tid >> 6;
    const int bm = blockIdx.y;
    const int bn = blockIdx.x;

    // --- staging addressing: wave-uniform LDS base + lane*16B (global_load_lds contract) ---
    // lane covers: row = lane/4 (16 rows/wave), 16B chunk c = lane%4 within the 64B row (BK=32 bf16)
    const int srow   = wave * 16 + (lane >> 2);
    const int schunk = (lane & 3) * 8;  // bf16 element offset in row

    const unsigned short* a_g0 = A  + (size_t)(bm * BM + srow) * K_TOT + schunk;
    const unsigned short* a_g1 = a_g0 + (size_t)64 * K_TOT;
    const unsigned short* b_g0 = Bw + (size_t)(bn * BN + srow) * K_TOT + schunk;
    const unsigned short* b_g1 = b_g0 + (size_t)64 * K_TOT;

    unsigned short* a_l0 = Asm + (wave * 16) * BK;        // wave-uniform
    unsigned short* a_l1 = Asm + (64 + wave * 16) * BK;
    unsigned short* b_l0 = Bsm + (wave * 16) * BK;
    unsigned short* b_l1 = Bsm + (64 + wave * 16) * BK;

    // --- compute-side lane mapping ---
    const int wm = (wave >> 1) * 64;   // wave's m-offset in tile
    const int wn = (wave & 1) * 64;    // wave's n-offset in tile
    const int mrow = lane & 15;        // A/B operand: m (or n) = lane&15
    const int quad = lane >> 4;        // k-quad: k = quad*8 + j

    float4v acc[4][4] = {};

    for (int k0 = 0; k0 < K_TOT; k0 += BK) {
        __syncthreads();   // previous iter's ds_reads done before overwrite
        __builtin_amdgcn_global_load_lds(
            (const __attribute__((address_space(1))) unsigned int*)(a_g0 + k0),
            (__attribute__((address_space(3))) unsigned int*)a_l0, 16, 0, 0);
        __builtin_amdgcn_global_load_lds(
            (const __attribute__((address_space(1))) unsigned int*)(a_g1 + k0),
            (__attribute__((address_space(3))) unsigned int*)a_l1, 16, 0, 0);
        __builtin_amdgcn_global_load_lds(
            (const __attribute__((address_space(1))) unsigned int*)(b_g0 + k0),
            (__attribute__((address_space(3))) unsigned int*)b_l0, 16, 0, 0);
        __builtin_amdgcn_global_load_lds(
            (const __attribute__((address_space(1))) unsigned int*)(b_g1 + k0),
            (__attribute__((address_space(3))) unsigned int*)b_l1, 16, 0, 0);
        __syncthreads();   // staging visible (compiler emits vmcnt(0) before barrier)

        short8 af[4], bf_[4];
#pragma unroll
        for (int mi = 0; mi < 4; ++mi)
            af[mi] = *(const short8*)(Asm + (wm + mi * 16 + mrow) * BK + quad * 8);
#pragma unroll
        for (int ni = 0; ni < 4; ++ni)
            bf_[ni] = *(const short8*)(Bsm + (wn + ni * 16 + mrow) * BK + quad * 8);

#pragma unroll
        for (int mi = 0; mi < 4; ++mi)
#pragma unroll
            for (int ni = 0; ni < 4; ++ni)
                acc[mi][ni] = __builtin_amdgcn_mfma_f32_16x16x32_bf16(
                    af[mi], bf_[ni], acc[mi][ni], 0, 0, 0);
    }

    // --- epilogue: C/D layout col = lane&15, row = quad*4 + reg; fuse bias ---
#pragma unroll
    for (int ni = 0; ni < 4; ++ni) {
        const int col = bn * BN + wn + ni * 16 + mrow;
        const float bv = bias[col];
#pragma unroll
        for (int mi = 0; mi < 4; ++mi) {
#pragma unroll
            for (int r = 0; r < 4; ++r) {
                const int row = bm * BM + wm + mi * 16 + quad * 4 + r;
                C[(size_t)row * N_TOT + col] = acc[mi][ni][r] + bv;
            }
        }
    }
}

extern "C" void kernel_launch(void* const* d_in, const int* in_sizes, int n_in,
                              void* d_out, int out_size, void* d_ws, size_t ws_size,
                              hipStream_t stream) {
    const float* x      = (const float*)d_in[0];
    const float* W_val  = (const float*)d_in[1];
    const float* bias   = (const float*)d_in[2];
    const int*   indices = (const int*)d_in[3];
    const int*   indptr  = (const int*)d_in[4];
    float* out = (float*)d_out;

    // workspace layout: [x_bf16: 16384*2048*2 = 64 MiB][W_bf16: 2048*2048*2 = 8 MiB]
    unsigned short* xb = (unsigned short*)d_ws;
    unsigned short* Wb = xb + (size_t)M_TOT * K_TOT;
    if (ws_size < ((size_t)M_TOT * K_TOT + (size_t)N_TOT * K_TOT) * sizeof(unsigned short))
        return;  // insufficient scratch; cannot proceed

    // 1) cast x: 33,554,432 floats / 8 per thread / 256 per block = 16384 blocks
    cast_x_kernel<<<16384, 256, 0, stream>>>(x, xb);
    // 2) zero W: 8,388,608 B / 16 B = 524,288 float4 / 256 = 2048 blocks
    zero_kernel<<<2048, 256, 0, stream>>>((float4*)Wb);
    // 3) scatter nnz into dense W
    scatter_kernel<<<N_TOT, 256, 0, stream>>>(W_val, indices, indptr, Wb);
    // 4) GEMM + bias
    dim3 grid(N_TOT / BN, M_TOT / BM);  // (16, 128) = 2048 blocks
    gemm_bias_kernel<<<grid, 256, 0, stream>>>(xb, Wb, bias, out);
}